// Round 6
// baseline (597.547 us; speedup 1.0000x reference)
//
#include <hip/hip_runtime.h>
#include <math.h>

#define EPS 1e-8f
#define LAMBDA 1e-3f

__device__ __forceinline__ float redsum32(float v) {
  #pragma unroll
  for (int off = 16; off >= 1; off >>= 1) v += __shfl_xor(v, off, 32);
  return v;
}
__device__ __forceinline__ float redmax32(float v) {
  #pragma unroll
  for (int off = 16; off >= 1; off >>= 1) v = fmaxf(v, __shfl_xor(v, off, 32));
  return v;
}

// One block per output row n (508 rows). 1024 threads = 32 chunks x 32 c.
// Thread (chunk,c) owns capsule c for B = chunk + 32*i, i in [0,9).
// WHY 1024: total waves = 508*16 = 8128 ~= the chip's 8192 wave slots.
// (R5's 256-thr blocks gave 2032 waves -> 25% occupancy hard cap; the grid,
// not per-CU limits, was the binding constraint.)
// LDS ~59.5 KB -> 2 blocks/CU; 2*16 waves = 32/CU = 100% cap. That needs
// VGPR <= 64 (binary cliff: 65+ -> 1 block/CU); allocator picked 64 unforced
// in R2/R4/R5 with this same loop body, so pin it with (1024, 8).
// su = sum_c(r*a) == a exactly (softmax sums to 1) -> folded into af.
__launch_bounds__(1024, 8)
__global__ void convcaps_kernel(const float* __restrict__ x,
                                const float* __restrict__ wgl,
                                const float* __restrict__ beta_u,
                                const float* __restrict__ beta_a,
                                float* __restrict__ out) {
  __shared__ float xr[288][16];       // pose patches, 18 KB
  __shared__ float a_sh[288];         // a/(a+EPS)
  __shared__ float red[17][512];      // two-phase reduction scratch, 34.8 KB
  __shared__ float mu_l[16][32];      // [s][c]
  __shared__ float i2s_l[16][32];     // 1/(2*sigma)
  __shared__ float hl_l[16][32];      // 0.5*ln(sigma)
  __shared__ float S_l[32];
  __shared__ float aout_l[32];
  __shared__ float lnao_l[32];

  const int tid = threadIdx.x;
  const int n = blockIdx.x;
  const int c = tid & 31;
  const int chunk = tid >> 5;         // 0..31

  // ---- stage 9 source rows (float4): xr[B][s], a_sh[B]=a/(a+EPS) ----
  for (int idx = tid; idx < 1224; idx += 1024) {   // 9 * 136 float4
    int t = idx / 136;
    int e4 = idx - t * 136;
    int g = 9 * n + t;
    int bg = g / 2286;                 // 2286 = 9*254
    int ki = (g % 2286) / 762;         // 762 = 3*254
    int owp = g % 254;
    const float4* src = reinterpret_cast<const float4*>(x) +
                        (size_t)((bg * 256 + ki + owp) * 4) * 136;
    float4 val = src[e4];
    if (e4 < 128) {
      reinterpret_cast<float4*>(&xr[0][0])[t * 128 + e4] = val;
    } else {
      val.x = val.x / (val.x + EPS);
      val.y = val.y / (val.y + EPS);
      val.z = val.z / (val.z + EPS);
      val.w = val.w / (val.w + EPS);
      reinterpret_cast<float4*>(a_sh)[t * 8 + (e4 - 128)] = val;
    }
  }
  __syncthreads();

  float A1[16], A2[16], Ssum;
  float mu[16], i2s[16];
  const size_t rbase = 276352;         // 2*254*544

  for (int pass = 0; pass < 3; ++pass) {
    #pragma unroll
    for (int s = 0; s < 16; ++s) { A1[s] = 0.f; A2[s] = 0.f; }
    Ssum = 0.f;
    float bias = 0.f;
    if (pass > 0) {
      float Hl = 0.f;
      #pragma unroll
      for (int s = 0; s < 16; ++s) {
        mu[s] = mu_l[s][c];            // broadcast across waves: conflict-free
        i2s[s] = i2s_l[s][c];
        Hl += hl_l[s][c];
      }
      bias = lnao_l[c] - Hl;
    }

    for (int i = 0; i < 9; ++i) {
      int B = chunk + 32 * i;          // wave touches adjacent B -> 256B r-lines
      const float4* wp = reinterpret_cast<const float4*>(wgl + ((size_t)(B * 32 + c)) * 16);
      float4 w0 = wp[0], w1 = wp[1], w2 = wp[2], w3 = wp[3];
      const float4* xp = reinterpret_cast<const float4*>(&xr[B][0]);
      float4 xv0 = xp[0], xv1 = xp[1], xv2 = xp[2], xv3 = xp[3];
      float v[16];
      {
        float x0 = xv0.x, x1 = xv0.y, x2 = xv0.z, x3 = xv0.w;
        v[0] = fmaf(x3, w3.x, fmaf(x2, w2.x, fmaf(x1, w1.x, x0 * w0.x)));
        v[1] = fmaf(x3, w3.y, fmaf(x2, w2.y, fmaf(x1, w1.y, x0 * w0.y)));
        v[2] = fmaf(x3, w3.z, fmaf(x2, w2.z, fmaf(x1, w1.z, x0 * w0.z)));
        v[3] = fmaf(x3, w3.w, fmaf(x2, w2.w, fmaf(x1, w1.w, x0 * w0.w)));
      }
      {
        float x0 = xv1.x, x1 = xv1.y, x2 = xv1.z, x3 = xv1.w;
        v[4] = fmaf(x3, w3.x, fmaf(x2, w2.x, fmaf(x1, w1.x, x0 * w0.x)));
        v[5] = fmaf(x3, w3.y, fmaf(x2, w2.y, fmaf(x1, w1.y, x0 * w0.y)));
        v[6] = fmaf(x3, w3.z, fmaf(x2, w2.z, fmaf(x1, w1.z, x0 * w0.z)));
        v[7] = fmaf(x3, w3.w, fmaf(x2, w2.w, fmaf(x1, w1.w, x0 * w0.w)));
      }
      {
        float x0 = xv2.x, x1 = xv2.y, x2 = xv2.z, x3 = xv2.w;
        v[8]  = fmaf(x3, w3.x, fmaf(x2, w2.x, fmaf(x1, w1.x, x0 * w0.x)));
        v[9]  = fmaf(x3, w3.y, fmaf(x2, w2.y, fmaf(x1, w1.y, x0 * w0.y)));
        v[10] = fmaf(x3, w3.z, fmaf(x2, w2.z, fmaf(x1, w1.z, x0 * w0.z)));
        v[11] = fmaf(x3, w3.w, fmaf(x2, w2.w, fmaf(x1, w1.w, x0 * w0.w)));
      }
      {
        float x0 = xv3.x, x1 = xv3.y, x2 = xv3.z, x3 = xv3.w;
        v[12] = fmaf(x3, w3.x, fmaf(x2, w2.x, fmaf(x1, w1.x, x0 * w0.x)));
        v[13] = fmaf(x3, w3.y, fmaf(x2, w2.y, fmaf(x1, w1.y, x0 * w0.y)));
        v[14] = fmaf(x3, w3.z, fmaf(x2, w2.z, fmaf(x1, w1.z, x0 * w0.z)));
        v[15] = fmaf(x3, w3.w, fmaf(x2, w2.w, fmaf(x1, w1.w, x0 * w0.w)));
      }

      float af = a_sh[B];
      float wgt;
      if (pass == 0) {
        wgt = af * 0.03125f;
      } else {
        // 4 parallel chains -> dependency depth ~6 instead of 16
        float t0, t1, t2, t3;
        {
          float d0 = v[0] - mu[0], d1 = v[1] - mu[1], d2 = v[2] - mu[2], d3 = v[3] - mu[3];
          t0 = d0*d0*i2s[0]; t1 = d1*d1*i2s[1]; t2 = d2*d2*i2s[2]; t3 = d3*d3*i2s[3];
        }
        #pragma unroll
        for (int q = 1; q < 4; ++q) {
          float d0 = v[q*4+0] - mu[q*4+0];
          float d1 = v[q*4+1] - mu[q*4+1];
          float d2 = v[q*4+2] - mu[q*4+2];
          float d3 = v[q*4+3] - mu[q*4+3];
          t0 = fmaf(d0*d0, i2s[q*4+0], t0);
          t1 = fmaf(d1*d1, i2s[q*4+1], t1);
          t2 = fmaf(d2*d2, i2s[q*4+2], t2);
          t3 = fmaf(d3*d3, i2s[q*4+3], t3);
        }
        float acc = (t0 + t1) + (t2 + t3);
        float lnap = bias - acc;
        float mx = redmax32(lnap);
        float e = __expf(lnap - mx);
        float se = redsum32(e);
        float r2 = e * __builtin_amdgcn_rcpf(se);
        if (pass == 2) out[rbase + ((size_t)n * 288 + B) * 32 + c] = r2;
        wgt = r2 * af;
      }
      #pragma unroll
      for (int s = 0; s < 16; ++s) {
        float p = wgt * v[s];
        A1[s] += p;
        A2[s] = fmaf(p, v[s], A2[s]);
      }
      Ssum += wgt;
    }

    // ---- cross-half pre-reduce, then two-phase LDS reduction over 16 waves ----
    #pragma unroll
    for (int s = 0; s < 16; ++s) {
      A1[s] += __shfl_xor(A1[s], 32, 64);
      A2[s] += __shfl_xor(A2[s], 32, 64);
    }
    Ssum += __shfl_xor(Ssum, 32, 64);
    const int col = (tid >> 6) * 32 + c;     // wave id * 32 + c, 0..511
    const bool writer = (tid & 63) < 32;

    // phase A: A1 + Ssum
    if (writer) {
      #pragma unroll
      for (int s = 0; s < 16; ++s) red[s][col] = A1[s];
      red[16][col] = Ssum;
    }
    __syncthreads();
    // 512 tasks (s,c) on threads 0..511
    float m_keep = 0.f, Sc_keep = 0.f, inv_keep = 0.f;
    const int s_t = tid >> 5;                // 0..15 for tid<512
    if (tid < 512) {
      float a1 = 0.f, ss = 0.f;
      #pragma unroll
      for (int ch = 0; ch < 16; ++ch) {
        int cl = ch * 32 + c;
        a1 += red[s_t][cl];
        ss += red[16][cl];
      }
      float inv = __builtin_amdgcn_rcpf(ss + EPS);
      float m = a1 * inv;
      mu_l[s_t][c] = m;
      m_keep = m; Sc_keep = ss * inv; inv_keep = inv;
      if (s_t == 0) S_l[c] = ss;
    }
    __syncthreads();

    // phase B: A2 reuses the buffer
    if (writer) {
      #pragma unroll
      for (int s = 0; s < 16; ++s) red[s][col] = A2[s];
    }
    __syncthreads();
    if (tid < 512) {
      float a2 = 0.f;
      #pragma unroll
      for (int ch = 0; ch < 16; ++ch) a2 += red[s_t][ch * 32 + c];
      float m = m_keep;
      float sg = fmaf(-m * m, 2.0f - Sc_keep, a2 * inv_keep) + EPS; // sigma_sq
      i2s_l[s_t][c] = 0.5f * __builtin_amdgcn_rcpf(sg);
      hl_l[s_t][c] = 0.5f * __logf(sg);
    }
    __syncthreads();

    if (tid < 32) {
      float sh = 0.f;
      #pragma unroll
      for (int s = 0; s < 16; ++s) sh += hl_l[s][tid];
      float cost = fmaf(beta_u[tid], 16.0f, sh) * S_l[tid];
      float z = LAMBDA * (beta_a[tid] - cost);
      float ao = __builtin_amdgcn_rcpf(1.0f + __expf(-z));
      aout_l[tid] = ao;
      lnao_l[tid] = __logf(ao);
    }
    __syncthreads();
  }

  // ---- outputs: row n = [mu (512) | a_out (32)], coalesced global ----
  if (tid < 512) {
    out[(size_t)n * 544 + tid] = mu_l[tid & 15][tid >> 4];
  } else if (tid < 544) {
    out[(size_t)n * 544 + tid] = aout_l[tid - 512];
  }
}

extern "C" void kernel_launch(void* const* d_in, const int* in_sizes, int n_in,
                              void* d_out, int out_size, void* d_ws, size_t ws_size,
                              hipStream_t stream) {
  const float* x  = (const float*)d_in[0];
  const float* w  = (const float*)d_in[1];
  const float* bu = (const float*)d_in[2];
  const float* ba = (const float*)d_in[3];
  float* out = (float*)d_out;
  convcaps_kernel<<<dim3(508), dim3(1024), 0, stream>>>(x, w, bu, ba, out);
}

// Round 7
// 166.177 us; speedup vs baseline: 3.5958x; 3.5958x over previous
//
#include <hip/hip_runtime.h>
#include <math.h>

#define EPS 1e-8f
#define LAMBDA 1e-3f

// One block per output row n (508 rows). 512 threads = 16 chunks x 32 c.
// Thread (chunk,c) owns capsule c for B in [chunk*18, chunk*18+18).
// R2 config (the only proven spill-free fast point: VGPR cap 128, 60KB LDS,
// 2 blocks/CU) + 2-way B-unroll so the two softmax shuffle chains interleave
// (ILP attack on VALUBusy=50%), + algebraic e-step: acc = sum v*(v*i2s+q2)+Q.
// DO NOT raise min-waves: caps <128 VGPR starve this body and spill
// (R3: 40 VGPR -> 633MB fetch; R6: 32 VGPR -> 1GB fetch).
__launch_bounds__(512, 4)
__global__ void convcaps_kernel(const float* __restrict__ x,
                                const float* __restrict__ wgl,
                                const float* __restrict__ beta_u,
                                const float* __restrict__ beta_a,
                                float* __restrict__ out) {
  __shared__ float xr[288][16];       // pose patches, 18 KB
  __shared__ float a_sh[288];         // a/(a+EPS)
  __shared__ float red[33][256];      // single-phase reduction scratch, 33.8 KB
  __shared__ float mu_l[16][33];      // [s][c], +1 pad
  __shared__ float i2s_l[16][33];     // 1/(2*sigma)
  __shared__ float hl_l[16][33];      // 0.5*ln(sigma)
  __shared__ float S_l[32];
  __shared__ float aout_l[32];
  __shared__ float lnao_l[32];

  const int tid = threadIdx.x;
  const int n = blockIdx.x;
  const int c = tid & 31;
  const int chunk = tid >> 5;         // 0..15

  // ---- stage 9 source rows (float4): xr[B][s], a_sh[B]=a/(a+EPS) ----
  for (int idx = tid; idx < 1224; idx += 512) {   // 9 * 136 float4
    int t = idx / 136;
    int e4 = idx - t * 136;
    int g = 9 * n + t;
    int bg = g / 2286;                 // 2286 = 9*254
    int ki = (g % 2286) / 762;         // 762 = 3*254
    int owp = g % 254;
    const float4* src = reinterpret_cast<const float4*>(x) +
                        (size_t)((bg * 256 + ki + owp) * 4) * 136;
    float4 val = src[e4];
    if (e4 < 128) {
      reinterpret_cast<float4*>(&xr[0][0])[t * 128 + e4] = val;
    } else {
      val.x = val.x / (val.x + EPS);
      val.y = val.y / (val.y + EPS);
      val.z = val.z / (val.z + EPS);
      val.w = val.w / (val.w + EPS);
      reinterpret_cast<float4*>(a_sh)[t * 8 + (e4 - 128)] = val;
    }
  }
  __syncthreads();

  float A1[16], A2[16], Ssum;
  float i2s[16], q2[16];
  const size_t rbase = 276352;         // 2*254*544

  for (int pass = 0; pass < 3; ++pass) {
    #pragma unroll
    for (int s = 0; s < 16; ++s) { A1[s] = 0.f; A2[s] = 0.f; }
    Ssum = 0.f;
    float bias = 0.f;
    if (pass > 0) {
      float Hl = 0.f, Q = 0.f;
      #pragma unroll
      for (int s = 0; s < 16; ++s) {
        float m = mu_l[s][c];
        float is = i2s_l[s][c];
        i2s[s] = is;
        q2[s] = -2.f * m * is;
        Q = fmaf(m * m, is, Q);
        Hl += hl_l[s][c];
      }
      bias = lnao_l[c] - Hl - Q;       // lnap = bias - sum v*(v*i2s+q2)
    }

    for (int ii = 0; ii < 9; ++ii) {
      const int B0 = chunk * 18 + 2 * ii;
      const int B1 = B0 + 1;
      float v0[16], v1[16];
      // ---- v for B0 ----
      {
        const float4* wp = reinterpret_cast<const float4*>(wgl + ((size_t)(B0 * 32 + c)) * 16);
        float4 w0 = wp[0], w1 = wp[1], w2 = wp[2], w3 = wp[3];
        const float4* xp = reinterpret_cast<const float4*>(&xr[B0][0]);
        #pragma unroll
        for (int r4 = 0; r4 < 4; ++r4) {
          float4 xv = xp[r4];
          v0[r4*4+0] = fmaf(xv.w, w3.x, fmaf(xv.z, w2.x, fmaf(xv.y, w1.x, xv.x * w0.x)));
          v0[r4*4+1] = fmaf(xv.w, w3.y, fmaf(xv.z, w2.y, fmaf(xv.y, w1.y, xv.x * w0.y)));
          v0[r4*4+2] = fmaf(xv.w, w3.z, fmaf(xv.z, w2.z, fmaf(xv.y, w1.z, xv.x * w0.z)));
          v0[r4*4+3] = fmaf(xv.w, w3.w, fmaf(xv.z, w2.w, fmaf(xv.y, w1.w, xv.x * w0.w)));
        }
      }
      // ---- v for B1 ----
      {
        const float4* wp = reinterpret_cast<const float4*>(wgl + ((size_t)(B1 * 32 + c)) * 16);
        float4 w0 = wp[0], w1 = wp[1], w2 = wp[2], w3 = wp[3];
        const float4* xp = reinterpret_cast<const float4*>(&xr[B1][0]);
        #pragma unroll
        for (int r4 = 0; r4 < 4; ++r4) {
          float4 xv = xp[r4];
          v1[r4*4+0] = fmaf(xv.w, w3.x, fmaf(xv.z, w2.x, fmaf(xv.y, w1.x, xv.x * w0.x)));
          v1[r4*4+1] = fmaf(xv.w, w3.y, fmaf(xv.z, w2.y, fmaf(xv.y, w1.y, xv.x * w0.y)));
          v1[r4*4+2] = fmaf(xv.w, w3.z, fmaf(xv.z, w2.z, fmaf(xv.y, w1.z, xv.x * w0.z)));
          v1[r4*4+3] = fmaf(xv.w, w3.w, fmaf(xv.z, w2.w, fmaf(xv.y, w1.w, xv.x * w0.w)));
        }
      }

      const float af0 = a_sh[B0];
      const float af1 = a_sh[B1];
      float wgt0, wgt1;
      if (pass == 0) {
        wgt0 = af0 * 0.03125f;
        wgt1 = af1 * 0.03125f;
      } else {
        // acc = sum_s v*(v*i2s + q2); 4 parallel chains per B, both B's in flight
        float a00 = 0.f, a01 = 0.f, a02 = 0.f, a03 = 0.f;
        float a10 = 0.f, a11 = 0.f, a12 = 0.f, a13 = 0.f;
        #pragma unroll
        for (int q = 0; q < 4; ++q) {
          a00 = fmaf(v0[q*4+0], fmaf(v0[q*4+0], i2s[q*4+0], q2[q*4+0]), a00);
          a10 = fmaf(v1[q*4+0], fmaf(v1[q*4+0], i2s[q*4+0], q2[q*4+0]), a10);
          a01 = fmaf(v0[q*4+1], fmaf(v0[q*4+1], i2s[q*4+1], q2[q*4+1]), a01);
          a11 = fmaf(v1[q*4+1], fmaf(v1[q*4+1], i2s[q*4+1], q2[q*4+1]), a11);
          a02 = fmaf(v0[q*4+2], fmaf(v0[q*4+2], i2s[q*4+2], q2[q*4+2]), a02);
          a12 = fmaf(v1[q*4+2], fmaf(v1[q*4+2], i2s[q*4+2], q2[q*4+2]), a12);
          a03 = fmaf(v0[q*4+3], fmaf(v0[q*4+3], i2s[q*4+3], q2[q*4+3]), a03);
          a13 = fmaf(v1[q*4+3], fmaf(v1[q*4+3], i2s[q*4+3], q2[q*4+3]), a13);
        }
        float lnap0 = bias - ((a00 + a01) + (a02 + a03));
        float lnap1 = bias - ((a10 + a11) + (a12 + a13));
        // interleaved max-butterflies (two independent shuffle chains)
        float m0 = lnap0, m1 = lnap1;
        #pragma unroll
        for (int off = 16; off >= 1; off >>= 1) {
          float o0 = __shfl_xor(m0, off, 32);
          float o1 = __shfl_xor(m1, off, 32);
          m0 = fmaxf(m0, o0);
          m1 = fmaxf(m1, o1);
        }
        float e0 = __expf(lnap0 - m0);
        float e1 = __expf(lnap1 - m1);
        float s0 = e0, s1 = e1;
        #pragma unroll
        for (int off = 16; off >= 1; off >>= 1) {
          float o0 = __shfl_xor(s0, off, 32);
          float o1 = __shfl_xor(s1, off, 32);
          s0 += o0;
          s1 += o1;
        }
        float r20 = e0 * __builtin_amdgcn_rcpf(s0);
        float r21 = e1 * __builtin_amdgcn_rcpf(s1);
        if (pass == 2) {
          out[rbase + ((size_t)n * 288 + B0) * 32 + c] = r20;
          out[rbase + ((size_t)n * 288 + B1) * 32 + c] = r21;
        }
        wgt0 = r20 * af0;
        wgt1 = r21 * af1;
      }
      #pragma unroll
      for (int s = 0; s < 16; ++s) {
        float p0 = wgt0 * v0[s];
        float p1 = wgt1 * v1[s];
        A1[s] += p0 + p1;
        A2[s] = fmaf(p0, v0[s], fmaf(p1, v1[s], A2[s]));
      }
      Ssum += wgt0 + wgt1;
    }

    // ---- cross-half pre-reduce, single-phase LDS reduction over 8 waves ----
    #pragma unroll
    for (int s = 0; s < 16; ++s) {
      A1[s] += __shfl_xor(A1[s], 32, 64);
      A2[s] += __shfl_xor(A2[s], 32, 64);
    }
    Ssum += __shfl_xor(Ssum, 32, 64);
    if ((tid & 63) < 32) {
      int col = (tid >> 6) * 32 + c;   // 0..255
      #pragma unroll
      for (int s = 0; s < 16; ++s) { red[s][col] = A1[s]; red[16 + s][col] = A2[s]; }
      red[32][col] = Ssum;
    }
    __syncthreads();

    // finalize: one (s_t, c2) task per thread
    {
      const int s_t = tid >> 5;        // 0..15
      const int c2 = tid & 31;
      float a1 = 0.f, a2 = 0.f, ss = 0.f;
      #pragma unroll
      for (int ch = 0; ch < 8; ++ch) {
        int cl = ch * 32 + c2;
        a1 += red[s_t][cl];
        a2 += red[16 + s_t][cl];
        ss += red[32][cl];
      }
      float inv = __builtin_amdgcn_rcpf(ss + EPS);
      float m = a1 * inv;
      float Sc = ss * inv;
      float sg = fmaf(-m * m, 2.0f - Sc, a2 * inv) + EPS;   // sigma_sq
      mu_l[s_t][c2] = m;
      i2s_l[s_t][c2] = 0.5f * __builtin_amdgcn_rcpf(sg);
      hl_l[s_t][c2] = 0.5f * __logf(sg);
      if (s_t == 0) S_l[c2] = ss;
    }
    __syncthreads();

    if (tid < 32) {
      float sh = 0.f;
      #pragma unroll
      for (int s = 0; s < 16; ++s) sh += hl_l[s][tid];
      float cost = fmaf(beta_u[tid], 16.0f, sh) * S_l[tid];
      float z = LAMBDA * (beta_a[tid] - cost);
      float ao = __builtin_amdgcn_rcpf(1.0f + __expf(-z));
      aout_l[tid] = ao;
      lnao_l[tid] = __logf(ao);
    }
    __syncthreads();
  }

  // ---- outputs: row n = [mu (512) | a_out (32)], coalesced global ----
  out[(size_t)n * 544 + tid] = mu_l[tid & 15][tid >> 4];
  if (tid < 32) out[(size_t)n * 544 + 512 + tid] = aout_l[tid];
}

extern "C" void kernel_launch(void* const* d_in, const int* in_sizes, int n_in,
                              void* d_out, int out_size, void* d_ws, size_t ws_size,
                              hipStream_t stream) {
  const float* x  = (const float*)d_in[0];
  const float* w  = (const float*)d_in[1];
  const float* bu = (const float*)d_in[2];
  const float* ba = (const float*)d_in[3];
  float* out = (float*)d_out;
  convcaps_kernel<<<dim3(508), dim3(512), 0, stream>>>(x, w, bu, ba, out);
}